// Round 1
// baseline (739.088 us; speedup 1.0000x reference)
//
#include <hip/hip_runtime.h>
#include <math.h>

#define L 512
#define E 128
#define BQ 64
#define BK 64
#define NT 8          // L / BK
#define SQ_LD 132     // padded leading dims (floats)
#define SK_LD 132
#define SS_LD 68
#define SV_LD 132

// ---------------------------------------------------------------------------
// Kernel A: prior + sigma_out.  One block per (bch, l) row; 128 threads,
// each writes one float4 of prior and one of sigma_out.  Memory-bound.
// ---------------------------------------------------------------------------
__global__ __launch_bounds__(128) void prior_kernel(
    const float* __restrict__ sigma,
    float* __restrict__ prior,
    float* __restrict__ sigma_out) {
  const int l = blockIdx.x;    // 0..511
  const int bch = blockIdx.y;  // 0..127

  const float x = sigma[bch * L + l];
  // sig = sigmoid(5x) + 1e-5 ; sigp = 3^sig - 1  (expm1 avoids cancellation)
  const float sg = 1.0f / (1.0f + expf(-5.0f * x)) + 1e-5f;
  const float sigp = expm1f(sg * 1.0986122886681098f);  // ln(3)
  const float inv_norm = 0.3989422804014327f / sigp;    // 1/sqrt(2*pi)/sigp
  const float c = -1.0f / (2.0f * sigp * sigp);

  const int m0 = threadIdx.x * 4;
  float4 pr, so;
  so.x = so.y = so.z = so.w = sigp;

  float d0 = (float)(l - (m0 + 0));
  float d1 = (float)(l - (m0 + 1));
  float d2 = (float)(l - (m0 + 2));
  float d3 = (float)(l - (m0 + 3));
  pr.x = inv_norm * __expf(c * d0 * d0);
  pr.y = inv_norm * __expf(c * d1 * d1);
  pr.z = inv_norm * __expf(c * d2 * d2);
  pr.w = inv_norm * __expf(c * d3 * d3);

  const size_t row = ((size_t)bch * L + l) * L + m0;
  *(float4*)(prior + row) = pr;
  *(float4*)(sigma_out + row) = so;
}

// ---------------------------------------------------------------------------
// Kernel B: causal attention (scores -> softmax -> series write + PV).
// Block = 256 threads handles one (bch, 64-row query tile).
// Thread (tq = tid/16, tk = tid%16): rows 4*tq..4*tq+3 (blocked),
// cols tk + 16*j (strided) of each 64x64 score tile.
// ---------------------------------------------------------------------------
__global__ __launch_bounds__(256, 2) void attn_kernel(
    const float* __restrict__ Q,
    const float* __restrict__ K,
    const float* __restrict__ V,
    float* __restrict__ outV,
    float* __restrict__ series) {
  const int qt = blockIdx.x;   // query tile 0..7 (block-uniform)
  const int bch = blockIdx.y;  // 0..127
  const int tid = threadIdx.x;
  const int tq = tid >> 4;     // 0..15
  const int tk = tid & 15;     // 0..15

  __shared__ float lds[16896];       // 66 KB -> 2 blocks/CU
  float* sQ = lds;                   // [64][SQ_LD]  phase 1
  float* sK = lds + 64 * SQ_LD;      // [64][SK_LD]  phase 1
  float* sS = lds;                   // [64][SS_LD]  phase 2 (overlaps sQ)
  float* sV = lds + 64 * SQ_LD;      // [64][SV_LD]  phase 2 (overlaps sK)

  const size_t base = (size_t)bch * L * E;
  const int qbase = qt * BQ;

  // ---- stage Q tile (64 x 128, coalesced float4) ----
#pragma unroll
  for (int i = 0; i < 8; ++i) {
    int fidx = i * 256 + tid;  // float4 index 0..2047
    int row = fidx >> 5;
    int e4 = fidx & 31;
    float4 v = *(const float4*)(Q + base + (size_t)(qbase + row) * E + e4 * 4);
    *(float4*)(sQ + row * SQ_LD + e4 * 4) = v;
  }
  __syncthreads();

  float Sreg[NT][4][4];
#pragma unroll
  for (int t = 0; t < NT; ++t)
#pragma unroll
    for (int i = 0; i < 4; ++i)
#pragma unroll
      for (int j = 0; j < 4; ++j) Sreg[t][i][j] = 0.0f;

  // ---- phase 1: scores ----
#pragma unroll
  for (int t = 0; t < NT; ++t) {
    if (t <= qt) {  // block-uniform branch
#pragma unroll
      for (int i = 0; i < 8; ++i) {
        int fidx = i * 256 + tid;
        int row = fidx >> 5;
        int e4 = fidx & 31;
        float4 v =
            *(const float4*)(K + base + (size_t)(t * BK + row) * E + e4 * 4);
        *(float4*)(sK + row * SK_LD + e4 * 4) = v;
      }
      __syncthreads();

      const float4* sQ4 = (const float4*)sQ;
      const float4* sK4 = (const float4*)sK;
#pragma unroll 2
      for (int e4 = 0; e4 < 32; ++e4) {
        float4 qv[4], kv[4];
#pragma unroll
        for (int i = 0; i < 4; ++i) qv[i] = sQ4[(4 * tq + i) * (SQ_LD / 4) + e4];
#pragma unroll
        for (int j = 0; j < 4; ++j)
          kv[j] = sK4[(tk + 16 * j) * (SK_LD / 4) + e4];
#pragma unroll
        for (int i = 0; i < 4; ++i)
#pragma unroll
          for (int j = 0; j < 4; ++j) {
            Sreg[t][i][j] = fmaf(qv[i].x, kv[j].x, Sreg[t][i][j]);
            Sreg[t][i][j] = fmaf(qv[i].y, kv[j].y, Sreg[t][i][j]);
            Sreg[t][i][j] = fmaf(qv[i].z, kv[j].z, Sreg[t][i][j]);
            Sreg[t][i][j] = fmaf(qv[i].w, kv[j].w, Sreg[t][i][j]);
          }
      }
      __syncthreads();  // before next tile's sK overwrite
    }
  }

  // ---- softmax over each query row (registers + 16-lane shfl reduce) ----
  const float scale = 0.08838834764831845f;  // 1/sqrt(128)
  float mrow[4], srow[4], inv[4];
#pragma unroll
  for (int i = 0; i < 4; ++i) mrow[i] = -__builtin_inff();

#pragma unroll
  for (int t = 0; t < NT; ++t) {
    if (t > qt) continue;
#pragma unroll
    for (int i = 0; i < 4; ++i)
#pragma unroll
      for (int j = 0; j < 4; ++j) {
        float s = Sreg[t][i][j] * scale;
        if (t == qt && (tk + 16 * j > 4 * tq + i)) s = -__builtin_inff();
        Sreg[t][i][j] = s;
        mrow[i] = fmaxf(mrow[i], s);
      }
  }
#pragma unroll
  for (int off = 1; off <= 8; off <<= 1)
#pragma unroll
    for (int i = 0; i < 4; ++i)
      mrow[i] = fmaxf(mrow[i], __shfl_xor(mrow[i], off, 64));

#pragma unroll
  for (int i = 0; i < 4; ++i) srow[i] = 0.0f;
#pragma unroll
  for (int t = 0; t < NT; ++t) {
    if (t > qt) continue;
#pragma unroll
    for (int i = 0; i < 4; ++i)
#pragma unroll
      for (int j = 0; j < 4; ++j) {
        float p = __expf(Sreg[t][i][j] - mrow[i]);  // exp(-inf)=0 for masked
        Sreg[t][i][j] = p;
        srow[i] += p;
      }
  }
#pragma unroll
  for (int off = 1; off <= 8; off <<= 1)
#pragma unroll
    for (int i = 0; i < 4; ++i) srow[i] += __shfl_xor(srow[i], off, 64);
#pragma unroll
  for (int i = 0; i < 4; ++i) inv[i] = 1.0f / srow[i];

  // ---- phase 2: series writes + PV ----
  float acc[4][8];
#pragma unroll
  for (int i = 0; i < 4; ++i)
#pragma unroll
    for (int c = 0; c < 8; ++c) acc[i][c] = 0.0f;
  const int te = tk;  // output cols te + 16*c

#pragma unroll
  for (int t = 0; t < NT; ++t) {
    __syncthreads();  // protect previous tile's sS/sV reads
    if (t <= qt) {    // block-uniform
      // stage normalized series tile into LDS
#pragma unroll
      for (int i = 0; i < 4; ++i)
#pragma unroll
        for (int j = 0; j < 4; ++j)
          sS[(4 * tq + i) * SS_LD + tk + 16 * j] = Sreg[t][i][j] * inv[i];
      // stage V tile
#pragma unroll
      for (int i2 = 0; i2 < 8; ++i2) {
        int fidx = i2 * 256 + tid;
        int row = fidx >> 5;
        int e4 = fidx & 31;
        float4 v =
            *(const float4*)(V + base + (size_t)(t * BK + row) * E + e4 * 4);
        *(float4*)(sV + row * SV_LD + e4 * 4) = v;
      }
      __syncthreads();

      // coalesced series write (64x64 tile)
      const float4* sS4 = (const float4*)sS;
#pragma unroll
      for (int i2 = 0; i2 < 4; ++i2) {
        int fidx = i2 * 256 + tid;  // 0..1023
        int srw = fidx >> 4;
        int c4 = fidx & 15;
        float4 v = sS4[srw * (SS_LD / 4) + c4];
        *(float4*)(series + ((size_t)bch * L + qbase + srw) * L + t * BK +
                   c4 * 4) = v;
      }

      // PV accumulate
      for (int m4 = 0; m4 < 16; ++m4) {
        float4 sr[4];
#pragma unroll
        for (int i = 0; i < 4; ++i)
          sr[i] = ((const float4*)sS)[(4 * tq + i) * (SS_LD / 4) + m4];
#pragma unroll
        for (int mm = 0; mm < 4; ++mm) {
          int m = 4 * m4 + mm;
          float vv[8];
#pragma unroll
          for (int c = 0; c < 8; ++c) vv[c] = sV[m * SV_LD + te + 16 * c];
#pragma unroll
          for (int i = 0; i < 4; ++i) {
            float sv = (mm == 0)   ? sr[i].x
                       : (mm == 1) ? sr[i].y
                       : (mm == 2) ? sr[i].z
                                   : sr[i].w;
#pragma unroll
            for (int c = 0; c < 8; ++c) acc[i][c] = fmaf(sv, vv[c], acc[i][c]);
          }
        }
      }
    } else {
      // fully-masked tile: series = 0
      float4 z = make_float4(0.f, 0.f, 0.f, 0.f);
#pragma unroll
      for (int i2 = 0; i2 < 4; ++i2) {
        int fidx = i2 * 256 + tid;
        int srw = fidx >> 4;
        int c4 = fidx & 15;
        *(float4*)(series + ((size_t)bch * L + qbase + srw) * L + t * BK +
                   c4 * 4) = z;
      }
    }
  }

  // ---- write V output ----
#pragma unroll
  for (int i = 0; i < 4; ++i)
#pragma unroll
    for (int c = 0; c < 8; ++c)
      outV[base + (size_t)(qbase + 4 * tq + i) * E + te + 16 * c] = acc[i][c];
}

// ---------------------------------------------------------------------------
extern "C" void kernel_launch(void* const* d_in, const int* in_sizes, int n_in,
                              void* d_out, int out_size, void* d_ws,
                              size_t ws_size, hipStream_t stream) {
  const float* Q = (const float*)d_in[0];
  const float* K = (const float*)d_in[1];
  const float* V = (const float*)d_in[2];
  const float* sigma = (const float*)d_in[3];
  // d_in[4] (attn_mask) ignored: it is deterministically triu(k=1).

  float* out = (float*)d_out;
  float* outV = out;                       //  8,388,608 floats
  float* series = out + 8388608;           // 33,554,432
  float* prior = out + 41943040;           // 33,554,432
  float* sigma_out = out + 75497472;       // 33,554,432

  attn_kernel<<<dim3(NT, 128), 256, 0, stream>>>(Q, K, V, outV, series);
  prior_kernel<<<dim3(L, 128), 128, 0, stream>>>(sigma, prior, sigma_out);
}

// Round 2
// 538.323 us; speedup vs baseline: 1.3729x; 1.3729x over previous
//
#include <hip/hip_runtime.h>
#include <math.h>

#define L 512
#define E 128
#define NT 8   // L / 64

typedef __attribute__((ext_vector_type(8))) short bf16x8;
typedef __attribute__((ext_vector_type(4))) float f32x4;
typedef __attribute__((ext_vector_type(4))) unsigned short u16x4;

__device__ __forceinline__ unsigned short bf16_rne(float x) {
  unsigned u = __builtin_bit_cast(unsigned, x);
  unsigned r = u + 0x7FFFu + ((u >> 16) & 1u);
  return (unsigned short)(r >> 16);
}
__device__ __forceinline__ float bf16_to_f(unsigned short h) {
  unsigned u = ((unsigned)h) << 16;
  return __builtin_bit_cast(float, u);
}

// ---------------------------------------------------------------------------
// prior + sigma_out: streaming writes, nontemporal. 2048 blocks x 256 thr.
// ---------------------------------------------------------------------------
__global__ __launch_bounds__(256) void prior_kernel(
    const float* __restrict__ sigma,
    float* __restrict__ prior,
    float* __restrict__ sigma_out) {
  const int half = threadIdx.x >> 7;   // 0,1
  const int t128 = threadIdx.x & 127;
  const int m0 = t128 * 4;
#pragma unroll 4
  for (int i = 0; i < 16; ++i) {
    const int row = blockIdx.x * 32 + i * 2 + half;  // bch*L + l
    const int l = row & (L - 1);
    const float x = sigma[row];
    const float sg = 1.0f / (1.0f + __expf(-5.0f * x)) + 1e-5f;
    const float sigp = expm1f(sg * 1.0986122886681098f);  // 3^sg - 1
    const float inv_norm = 0.3989422804014327f / sigp;
    const float c = -1.0f / (2.0f * sigp * sigp);

    f32x4 pr, so;
    so[0] = so[1] = so[2] = so[3] = sigp;
#pragma unroll
    for (int j = 0; j < 4; ++j) {
      float d = (float)(l - (m0 + j));
      pr[j] = inv_norm * __expf(c * d * d);
    }
    const size_t off = (size_t)row * L + m0;
    __builtin_nontemporal_store(pr, (f32x4*)(prior + off));
    __builtin_nontemporal_store(so, (f32x4*)(sigma_out + off));
  }
}

// ---------------------------------------------------------------------------
// MFMA attention. Block = 256 thr = 4 waves, one (bch, 64-row query tile).
// Wave w owns query rows 16w..16w+15. QK^T: bf16 hi/lo split (3 MFMAs).
// PV: single bf16. 16x16x32 MFMA; C/D layout col=lane&15, row=4*(lane>>4)+reg.
// ---------------------------------------------------------------------------
__global__ __launch_bounds__(256, 2) void attn_kernel(
    const float* __restrict__ Q,
    const float* __restrict__ K,
    const float* __restrict__ V,
    float* __restrict__ outV,
    float* __restrict__ series) {
  const int bch = blockIdx.x;  // 0..127 (x so same-head blocks share an XCD)
  const int qt = blockIdx.y;   // 0..7
  const int tid = threadIdx.x;
  const int w = tid >> 6, lane = tid & 63, r = lane & 15, g = lane >> 4;

  // LDS: phase1 Khi[64][136 bf16] + Klo (17408 B each)
  //      phase2 P[64][72 bf16] (9216 B) + Vt[128][72 bf16] (18432 B)
  __shared__ char smem[34816];
  char* sKhi = smem;
  char* sKlo = smem + 17408;
  char* sP = smem;
  char* sVt = smem + 9216;

  const size_t base = (size_t)bch * (L * E);
  const int qbase = qt * 64;
  const float scale = 0.08838834764831845f;  // 1/sqrt(128)

  // ---- Q fragments in registers (A operand), pre-scaled, hi/lo split ----
  bf16x8 qh[4], ql[4];
  {
    const float* qrow = Q + base + (size_t)(qbase + 16 * w + r) * E;
#pragma unroll
    for (int ks = 0; ks < 4; ++ks) {
      const int e0 = 32 * ks + 8 * g;
      f32x4 a = *(const f32x4*)(qrow + e0);
      f32x4 b = *(const f32x4*)(qrow + e0 + 4);
#pragma unroll
      for (int j = 0; j < 4; ++j) {
        float xa = a[j] * scale;
        unsigned short ha = bf16_rne(xa);
        qh[ks][j] = (short)ha;
        ql[ks][j] = (short)bf16_rne(xa - bf16_to_f(ha));
        float xb = b[j] * scale;
        unsigned short hb = bf16_rne(xb);
        qh[ks][4 + j] = (short)hb;
        ql[ks][4 + j] = (short)bf16_rne(xb - bf16_to_f(hb));
      }
    }
  }

  f32x4 Sacc[NT][4];
#pragma unroll
  for (int t = 0; t < NT; ++t)
#pragma unroll
    for (int cb = 0; cb < 4; ++cb) Sacc[t][cb] = (f32x4){0.f, 0.f, 0.f, 0.f};

  // ---- phase 1: scores via MFMA ----
#pragma unroll
  for (int t = 0; t < NT; ++t) {
    if (t <= qt) {
      __syncthreads();
      // stage K tile -> bf16 hi/lo, padded rows (136 bf16 = 272 B)
#pragma unroll
      for (int i = 0; i < 8; ++i) {
        int f = i * 256 + tid;
        int row = f >> 5;
        int e0 = (f & 31) * 4;
        f32x4 kv = *(const f32x4*)(K + base + (size_t)(t * 64 + row) * E + e0);
        u16x4 h4, l4;
#pragma unroll
        for (int j = 0; j < 4; ++j) {
          unsigned short h = bf16_rne(kv[j]);
          h4[j] = h;
          l4[j] = bf16_rne(kv[j] - bf16_to_f(h));
        }
        *(u16x4*)(sKhi + row * 272 + e0 * 2) = h4;
        *(u16x4*)(sKlo + row * 272 + e0 * 2) = l4;
      }
      __syncthreads();

#pragma unroll
      for (int ks = 0; ks < 4; ++ks) {
#pragma unroll
        for (int cb = 0; cb < 4; ++cb) {
          const int kb = (16 * cb + r) * 272 + (32 * ks + 8 * g) * 2;
          bf16x8 bh = *(const bf16x8*)(sKhi + kb);
          bf16x8 bl = *(const bf16x8*)(sKlo + kb);
          f32x4 acc = Sacc[t][cb];
          acc = __builtin_amdgcn_mfma_f32_16x16x32_bf16(qh[ks], bh, acc, 0, 0, 0);
          acc = __builtin_amdgcn_mfma_f32_16x16x32_bf16(ql[ks], bh, acc, 0, 0, 0);
          acc = __builtin_amdgcn_mfma_f32_16x16x32_bf16(qh[ks], bl, acc, 0, 0, 0);
          Sacc[t][cb] = acc;
        }
      }
    }
  }

  // ---- softmax (rows 16w+4g+reg; cols 16cb+r; reduce over r via shfl) ----
  float mrow[4], srow[4], inv[4];
#pragma unroll
  for (int reg = 0; reg < 4; ++reg) mrow[reg] = -__builtin_inff();

#pragma unroll
  for (int t = 0; t < NT; ++t) {
    if (t > qt) continue;
#pragma unroll
    for (int cb = 0; cb < 4; ++cb)
#pragma unroll
      for (int reg = 0; reg < 4; ++reg) {
        float s = Sacc[t][cb][reg];
        if (t == qt && (16 * cb + r) > (16 * w + 4 * g + reg))
          s = -__builtin_inff();
        Sacc[t][cb][reg] = s;
        mrow[reg] = fmaxf(mrow[reg], s);
      }
  }
#pragma unroll
  for (int off = 1; off <= 8; off <<= 1)
#pragma unroll
    for (int reg = 0; reg < 4; ++reg)
      mrow[reg] = fmaxf(mrow[reg], __shfl_xor(mrow[reg], off, 64));

#pragma unroll
  for (int reg = 0; reg < 4; ++reg) srow[reg] = 0.0f;
#pragma unroll
  for (int t = 0; t < NT; ++t) {
    if (t > qt) continue;
#pragma unroll
    for (int cb = 0; cb < 4; ++cb)
#pragma unroll
      for (int reg = 0; reg < 4; ++reg) {
        float p = __expf(Sacc[t][cb][reg] - mrow[reg]);
        Sacc[t][cb][reg] = p;
        srow[reg] += p;
      }
  }
#pragma unroll
  for (int off = 1; off <= 8; off <<= 1)
#pragma unroll
    for (int reg = 0; reg < 4; ++reg) srow[reg] += __shfl_xor(srow[reg], off, 64);
#pragma unroll
  for (int reg = 0; reg < 4; ++reg) inv[reg] = 1.0f / srow[reg];

  // ---- phase 2: P->LDS (bf16), Vt->LDS (bf16, transposed+swizzled),
  //      series write, PV MFMA ----
  f32x4 Oacc[8];
#pragma unroll
  for (int cb = 0; cb < 8; ++cb) Oacc[cb] = (f32x4){0.f, 0.f, 0.f, 0.f};

#pragma unroll
  for (int t = 0; t < NT; ++t) {
    if (t <= qt) {
      __syncthreads();
      // write normalized P (bf16) [q][m], row stride 144 B
#pragma unroll
      for (int cb = 0; cb < 4; ++cb)
#pragma unroll
        for (int reg = 0; reg < 4; ++reg) {
          float p = Sacc[t][cb][reg] * inv[reg];
          *(unsigned short*)(sP + (16 * w + 4 * g + reg) * 144 +
                             (16 * cb + r) * 2) = bf16_rne(p);
        }
      // stage V transposed: Vt[e][m], row 144 B, slot-swizzled by ((e>>2)&7)
#pragma unroll
      for (int bb = 0; bb < 2; ++bb) {
        int bidx = tid + 256 * bb;
        int m0 = (bidx >> 5) * 4;
        int e0 = (bidx & 31) * 4;
        const float* vrow = V + base + (size_t)(t * 64 + m0) * E + e0;
        f32x4 R0 = *(const f32x4*)(vrow);
        f32x4 R1 = *(const f32x4*)(vrow + E);
        f32x4 R2 = *(const f32x4*)(vrow + 2 * E);
        f32x4 R3 = *(const f32x4*)(vrow + 3 * E);
#pragma unroll
        for (int i = 0; i < 4; ++i) {
          u16x4 wv;
          wv[0] = bf16_rne(R0[i]);
          wv[1] = bf16_rne(R1[i]);
          wv[2] = bf16_rne(R2[i]);
          wv[3] = bf16_rne(R3[i]);
          int e = e0 + i;
          int byte = e * 144 + m0 * 2;
          byte ^= ((e >> 2) & 7) << 4;
          *(u16x4*)(sVt + byte) = wv;
        }
      }
      __syncthreads();

      // series write (f32 from bf16 P), coalesced
#pragma unroll
      for (int i = 0; i < 4; ++i) {
        int f = tid + 256 * i;
        int q = f >> 4, m4 = f & 15;
        u16x4 pv = *(const u16x4*)(sP + q * 144 + m4 * 8);
        f32x4 o;
        o[0] = bf16_to_f(pv[0]);
        o[1] = bf16_to_f(pv[1]);
        o[2] = bf16_to_f(pv[2]);
        o[3] = bf16_to_f(pv[3]);
        *(f32x4*)(series + ((size_t)bch * L + qbase + q) * L + t * 64 +
                  4 * m4) = o;
      }

      // PV MFMA: A = P rows (wave's q), B = Vt cols (e)
#pragma unroll
      for (int ks = 0; ks < 2; ++ks) {
        bf16x8 ap =
            *(const bf16x8*)(sP + (16 * w + r) * 144 + (32 * ks + 8 * g) * 2);
#pragma unroll
        for (int cb = 0; cb < 8; ++cb) {
          int e = 16 * cb + r;
          int byte = e * 144 + (32 * ks + 8 * g) * 2;
          byte ^= ((e >> 2) & 7) << 4;
          bf16x8 bv = *(const bf16x8*)(sVt + byte);
          Oacc[cb] = __builtin_amdgcn_mfma_f32_16x16x32_bf16(ap, bv, Oacc[cb],
                                                             0, 0, 0);
        }
      }
    }
  }

  // ---- masked tiles: series = 0 ----
#pragma unroll
  for (int t = 0; t < NT; ++t) {
    if (t > qt) {
      f32x4 z = (f32x4){0.f, 0.f, 0.f, 0.f};
#pragma unroll
      for (int i = 0; i < 4; ++i) {
        int f = tid + 256 * i;
        int q = f >> 4, m4 = f & 15;
        *(f32x4*)(series + ((size_t)bch * L + qbase + q) * L + t * 64 +
                  4 * m4) = z;
      }
    }
  }

  // ---- outV: rows q=16w+4g+reg, cols e=16cb+r ----
#pragma unroll
  for (int cb = 0; cb < 8; ++cb)
#pragma unroll
    for (int reg = 0; reg < 4; ++reg)
      outV[base + (size_t)(qbase + 16 * w + 4 * g + reg) * E + 16 * cb + r] =
          Oacc[cb][reg];
}

// ---------------------------------------------------------------------------
extern "C" void kernel_launch(void* const* d_in, const int* in_sizes, int n_in,
                              void* d_out, int out_size, void* d_ws,
                              size_t ws_size, hipStream_t stream) {
  const float* Q = (const float*)d_in[0];
  const float* K = (const float*)d_in[1];
  const float* V = (const float*)d_in[2];
  const float* sigma = (const float*)d_in[3];
  // d_in[4] (attn_mask) ignored: deterministically triu(k=1).

  float* out = (float*)d_out;
  float* outV = out;                  //  8,388,608 floats
  float* series = out + 8388608;      // 33,554,432
  float* prior = out + 41943040;      // 33,554,432
  float* sigma_out = out + 75497472;  // 33,554,432

  attn_kernel<<<dim3(128, NT), 256, 0, stream>>>(Q, K, V, outV, series);
  prior_kernel<<<dim3(2048), 256, 0, stream>>>(sigma, prior, sigma_out);
}